// Round 11
// baseline (326.053 us; speedup 1.0000x reference)
//
#include <hip/hip_runtime.h>
#include <hip/hip_bf16.h>
#include <math.h>

#define DM 1024
#define NH 16
#define HD 64
#define BB 2
#define TT 2048
#define MROWS (BB*TT)   // 4096
#define PL ((size_t)MROWS * DM)   // elements per activation plane (4 Mi)
#define PLW ((size_t)DM * DM)     // elements per weight plane (1 Mi)

using bf8_t = __attribute__((ext_vector_type(8))) __bf16;   // one MFMA A/B fragment (4 VGPRs)
using bf4_t = __attribute__((ext_vector_type(4))) __bf16;   // 8-byte LDS/global chunk
using f4_t  = __attribute__((ext_vector_type(4))) float;    // MFMA C/D fragment

typedef const __attribute__((address_space(1))) void* gas_t;
typedef __attribute__((address_space(3))) void* las_t;

// ---------------------------------------------------------------------------
// Fused prep (unchanged from round 10).
// ---------------------------------------------------------------------------
__global__ __launch_bounds__(256) void prep(
        const void* __restrict__ X,
        const void* __restrict__ w0, const void* __restrict__ w1,
        const void* __restrict__ w2, const void* __restrict__ w3,
        __bf16* __restrict__ Xh, __bf16* __restrict__ Wsp,
        float2* __restrict__ trig, int* __restrict__ flag)
{
    const int id  = (int)blockIdx.x;
    const int tid = (int)threadIdx.x;

    __shared__ int cnt;
    if (tid == 0) cnt = 0;
    __syncthreads();
    {
        int local = 0;
        const unsigned short* xu = (const unsigned short*)X;
        for (int i = tid; i < 512; i += 256) {
            const int e = (xu[i] >> 7) & 0xFF;
            if (e >= 117 && e <= 130) local++;
        }
        atomicAdd(&cnt, local);
    }
    __syncthreads();
    const int f32 = (cnt >= 384) ? 0 : 1;

    if (id >= 8448) {
        if (tid == 0) *flag = f32;
        return;
    }
    if (id >= 8192) {
        const int idx = (id - 8192) * 256 + tid;
        const int t = idx >> 5, ip = idx & 31;
        const float inv_freq = powf(10000.0f, -2.0f * (float)ip / 64.0f);
        const float ang = (float)t * inv_freq;
        float s, c;
        sincosf(ang, &s, &c);
        trig[idx] = make_float2(c, s);
        return;
    }

    const void* Src;
    __bf16 *Yh, *Yl;
    size_t i;
    if (id < 4096) {
        Src = X;
        Yh = Xh; Yl = Xh + PL;
        i = ((size_t)id * 256 + tid) * 4;
    } else {
        const int wid   = (id - 4096) >> 10;
        const int inner = (id - 4096) & 1023;
        Src = (wid == 0) ? w0 : (wid == 1) ? w1 : (wid == 2) ? w2 : w3;
        Yh = Wsp + (size_t)wid * 2 * PLW;
        Yl = Yh + PLW;
        i = ((size_t)inner * 256 + tid) * 4;
    }
    if (f32) {
        float4 v = *(const float4*)((const float*)Src + i);
        __bf16 h0 = (__bf16)v.x, h1 = (__bf16)v.y, h2 = (__bf16)v.z, h3 = (__bf16)v.w;
        bf4_t hv = {h0, h1, h2, h3};
        bf4_t lv = {(__bf16)(v.x - (float)h0), (__bf16)(v.y - (float)h1),
                    (__bf16)(v.z - (float)h2), (__bf16)(v.w - (float)h3)};
        *(bf4_t*)(Yh + i) = hv;
        *(bf4_t*)(Yl + i) = lv;
    } else {
        bf4_t v = *(const bf4_t*)((const __bf16*)Src + i);
        *(bf4_t*)(Yh + i) = v;
        bf4_t zv = {(__bf16)0.f, (__bf16)0.f, (__bf16)0.f, (__bf16)0.f};
        *(bf4_t*)(Yl + i) = zv;
    }
}

// ---------------------------------------------------------------------------
// XCD-aware bijective block remap (T1, nwg % 8 == 0 for all grids).
// ---------------------------------------------------------------------------
__device__ __forceinline__ int xcd_remap(int flat, int nwg) {
    return (flat & 7) * (nwg >> 3) + (flat >> 3);
}

__device__ __forceinline__ int swz(int r, int b) {
    return r * 128 + (b ^ ((r & 7) << 4));
}
#define VST 264

// ---------------------------------------------------------------------------
// MFMA GEMM v11: staging via global_load_lds width=16 into LINEAR LDS
// (m97 pattern; inputs are plain bf16 plane copies now).  Chunk index
// u = tid + j*256 makes the linear LDS dest = wave-uniform base + lane*16,
// exactly what the HW requires (rule 21: both-sides-or-neither -> neither).
// Reads are un-swizzled; m97 ran 874-912 TF with the same conflict pattern.
// 2-barrier loop: stage -> barrier (vmcnt drain) -> compute -> barrier.
// ---------------------------------------------------------------------------
__global__ __launch_bounds__(256, 3) void gemm_fused(
        const __bf16* __restrict__ Ahg,
        const __bf16* __restrict__ Wsp,
        __bf16* __restrict__ Y0, __bf16* __restrict__ Y1,
        __bf16* __restrict__ Y2,
        void* __restrict__ Yout,
        const float2* __restrict__ trig,
        const int* __restrict__ flag, const int outMode)
{
    const int f32 = *flag;

    const int nx = (int)gridDim.x, ny = (int)gridDim.y, nz = (int)gridDim.z;
    int flat = (int)blockIdx.x + nx * ((int)blockIdx.y + ny * (int)blockIdx.z);
    flat = xcd_remap(flat, nx * ny * nz);
    const int bx = flat % nx;
    const int rem = flat / nx;
    const int by = rem % ny;
    const int z  = rem / ny;

    const int widx = outMode ? 3 : z;
    const __bf16* Whg = Wsp + (size_t)widx * 2 * PLW;
    const __bf16* Wlg = Whg + PLW;
    const __bf16* Alg = Ahg + PL;
    const bool aLo = (outMode != 0) || (f32 != 0);
    const bool wLo = (f32 != 0);

    __shared__ __align__(16) char sm[49152];
    char* const AhL = sm;            // [128][64] bf16 linear (16 KB)
    char* const AlL = sm + 16384;
    char* const WhL = sm + 32768;    // [64][64] bf16 linear (8 KB)
    char* const WlL = sm + 40960;

    const int tid  = threadIdx.x;
    const int n0   = bx * 64, m0 = by * 128;
    const int lane = tid & 63;
    const int w    = tid >> 6;
    const int wr   = (w >> 1) * 64;
    const int wcn  = (w & 1) * 32;
    const int l15  = lane & 15;
    const int g    = lane >> 4;

    f4_t acc[4][2] = {};

    for (int k0 = 0; k0 < DM; k0 += 64) {
        if (k0) __syncthreads();     // previous compute done before overwrite

        // ---- stage via global_load_lds (linear LDS, wave-uniform base) ----
#pragma unroll
        for (int j = 0; j < 4; j++) {
            const int u = tid + j * 256, r = u >> 3, c = u & 7;
            char* const db = AhL + (size_t)(j * 256 + w * 64) * 16;
            __builtin_amdgcn_global_load_lds(
                (gas_t)(Ahg + (size_t)(m0 + r) * DM + k0 + c * 8),
                (las_t)db, 16, 0, 0);
            if (aLo)
                __builtin_amdgcn_global_load_lds(
                    (gas_t)(Alg + (size_t)(m0 + r) * DM + k0 + c * 8),
                    (las_t)(AlL + (size_t)(j * 256 + w * 64) * 16), 16, 0, 0);
        }
#pragma unroll
        for (int j = 0; j < 2; j++) {
            const int u = tid + j * 256, r = u >> 3, c = u & 7;
            __builtin_amdgcn_global_load_lds(
                (gas_t)(Whg + (size_t)(n0 + r) * DM + k0 + c * 8),
                (las_t)(WhL + (size_t)(j * 256 + w * 64) * 16), 16, 0, 0);
            if (wLo)
                __builtin_amdgcn_global_load_lds(
                    (gas_t)(Wlg + (size_t)(n0 + r) * DM + k0 + c * 8),
                    (las_t)(WlL + (size_t)(j * 256 + w * 64) * 16), 16, 0, 0);
        }
        __syncthreads();             // implicit vmcnt drain -> data ready

        // ---- compute (linear reads) ----
#pragma unroll
        for (int kh = 0; kh < 2; kh++) {
            const int bc = kh * 64 + g * 16;
            bf8_t ah[4], al[4], wh[2], wl[2];
#pragma unroll
            for (int m = 0; m < 4; m++) {
                ah[m] = *(const bf8_t*)(AhL + (wr + m * 16 + l15) * 128 + bc);
                if (aLo) al[m] = *(const bf8_t*)(AlL + (wr + m * 16 + l15) * 128 + bc);
            }
#pragma unroll
            for (int n = 0; n < 2; n++) {
                wh[n] = *(const bf8_t*)(WhL + (wcn + n * 16 + l15) * 128 + bc);
                if (wLo) wl[n] = *(const bf8_t*)(WlL + (wcn + n * 16 + l15) * 128 + bc);
            }
#pragma unroll
            for (int m = 0; m < 4; m++)
#pragma unroll
                for (int n = 0; n < 2; n++) {
                    acc[m][n] = __builtin_amdgcn_mfma_f32_16x16x32_bf16(
                                    ah[m], wh[n], acc[m][n], 0, 0, 0);
                    if (aLo)
                        acc[m][n] = __builtin_amdgcn_mfma_f32_16x16x32_bf16(
                                        al[m], wh[n], acc[m][n], 0, 0, 0);
                    if (wLo)
                        acc[m][n] = __builtin_amdgcn_mfma_f32_16x16x32_bf16(
                                        ah[m], wl[n], acc[m][n], 0, 0, 0);
                }
        }
    }

    const int orow = g * 4;
    const int ocol = l15;
    __syncthreads();

    if (outMode) {
        if (f32) {
#pragma unroll
            for (int m = 0; m < 4; m++)
#pragma unroll
                for (int n = 0; n < 2; n++) {
                    const int gr = m0 + wr + m * 16 + orow;
                    const int gc = n0 + wcn + n * 16 + ocol;
#pragma unroll
                    for (int r = 0; r < 4; r++)
                        ((float*)Yout)[(size_t)(gr + r) * DM + gc] = acc[m][n][r];
                }
        } else {
            char* const EhL = sm;
#pragma unroll
            for (int m = 0; m < 4; m++)
#pragma unroll
                for (int n = 0; n < 2; n++) {
                    const int ctile = wcn + n * 16 + ocol;
#pragma unroll
                    for (int r = 0; r < 4; r++) {
                        const int rtile = wr + m * 16 + orow + r;
                        *(__bf16*)(EhL + rtile * 128 + ctile * 2) = (__bf16)acc[m][n][r];
                    }
                }
            __syncthreads();
#pragma unroll
            for (int j = 0; j < 4; j++) {
                const int u = tid + j * 256, r = u >> 3, c = u & 7;
                *(bf8_t*)((__bf16*)Yout + (size_t)(m0 + r) * DM + n0 + c * 8) =
                    *(const bf8_t*)(EhL + r * 128 + c * 16);
            }
        }
    } else if (z == 2) {
        char* const EhL = sm;
        char* const ElL = sm + 20480;
#pragma unroll
        for (int m = 0; m < 4; m++)
#pragma unroll
            for (int n = 0; n < 2; n++) {
                const int ctile = wcn + n * 16 + ocol;
#pragma unroll
                for (int r = 0; r < 4; r++) {
                    const int rtile = wr + m * 16 + orow + r;
                    const float val = acc[m][n][r];
                    __bf16 hb = (__bf16)val;
                    *(__bf16*)(EhL + ctile * VST + rtile * 2) = hb;
                    *(__bf16*)(ElL + ctile * VST + rtile * 2) = (__bf16)(val - (float)hb);
                }
            }
        __syncthreads();
        __bf16* Vh = Y2;
        __bf16* Vl = Y2 + PL;
#pragma unroll
        for (int j = 0; j < 4; j++) {
            const int u = tid + j * 256, cc = u >> 4, k = u & 15;
            *(bf8_t*)(Vh + (size_t)(n0 + cc) * MROWS + m0 + k * 8) =
                *(const bf8_t*)(EhL + cc * VST + k * 16);
            *(bf8_t*)(Vl + (size_t)(n0 + cc) * MROWS + m0 + k * 8) =
                *(const bf8_t*)(ElL + cc * VST + k * 16);
        }
    } else {
        char* const EhL = sm;
        char* const ElL = sm + 20480;
#pragma unroll
        for (int m = 0; m < 4; m++)
#pragma unroll
            for (int n = 0; n < 2; n++) {
                const int ctile = wcn + n * 16 + ocol;
                const int gc = n0 + ctile;
                const int ip = (gc & 63) >> 1;
                const bool oddc = (gc & 1) != 0;
#pragma unroll
                for (int r = 0; r < 4; r++) {
                    const int rtile = wr + m * 16 + orow + r;
                    const int t = (m0 + rtile) & (TT - 1);
                    const float2 cs = trig[t * 32 + ip];
                    const float v = acc[m][n][r];
                    const float ov = __shfl_xor(v, 1);
                    float res = oddc ? (ov * cs.y + v * cs.x) : (v * cs.x - ov * cs.y);
                    if (z == 0) res *= 0.125f;
                    __bf16 hb = (__bf16)res;
                    *(__bf16*)(EhL + rtile * 128 + ctile * 2) = hb;
                    *(__bf16*)(ElL + rtile * 128 + ctile * 2) = (__bf16)(res - (float)hb);
                }
            }
        __syncthreads();
        __bf16* Yh = z ? Y1 : Y0;
        __bf16* Yl = Yh + PL;
#pragma unroll
        for (int j = 0; j < 4; j++) {
            const int u = tid + j * 256, r = u >> 3, c = u & 7;
            *(bf8_t*)(Yh + (size_t)(m0 + r) * DM + n0 + c * 8) =
                *(const bf8_t*)(EhL + r * 128 + c * 16);
            *(bf8_t*)(Yl + (size_t)(m0 + r) * DM + n0 + c * 8) =
                *(const bf8_t*)(ElL + r * 128 + c * 16);
        }
    }
}

// ---------------------------------------------------------------------------
// MFMA flash attention v11: 32 q-rows/wave (m=2) halves LDS ops per output
// row (K/V fragment reads amortize over 2x MFMA).  QBLK=128, KVBLK=64.
// Single 32KB KV buffer + reg-prefetch (v5 schedule: ISSUE(t+1) under
// compute, 2 barriers) + 32KB wave-private P -> 64KB, 2 blocks/CU.
// Fixed-max softmax + P-via-LDS verbatim from v9.  Largest-first remap.
// ---------------------------------------------------------------------------
__global__ void __launch_bounds__(256, 2) flash_attn_mfma(
        const __bf16* __restrict__ Qhg, const __bf16* __restrict__ Khg,
        const __bf16* __restrict__ Vhg, __bf16* __restrict__ Aoh)
{
    __shared__ __align__(16) char sm[65536];
    // KV: Kh +0, Kl +8192, Vh +16384, Vl +24576 (32 KB)
    // P/epilogue: sm + 32768 + w*8192 (hi @0, lo @4096)

    const __bf16* Qlg = Qhg + PL;
    const __bf16* Klg = Khg + PL;
    const __bf16* Vlg = Vhg + PL;
    __bf16* Aol = Aoh + PL;

    int flat = (int)blockIdx.x + 16 * ((int)blockIdx.y + 16 * (int)blockIdx.z);
    flat = xcd_remap(flat, 512);
    const int qt = 15 - (flat % 16);          // largest work first
    const int h  = (flat / 16) % 16;
    const int b  = flat / 256;

    const int tid = threadIdx.x;
    const int lane = tid & 63;
    const int w    = tid >> 6;
    const int l15  = lane & 15;
    const int g    = lane >> 4;

    char* const pb = sm + 32768 + w * 8192;   // wave-private P buffer

    // ---- Q fragments hi/lo (pre-scaled by 1/8 in GEMM epilogue) ----
    bf8_t qh[2][2], ql[2][2];
#pragma unroll
    for (int m = 0; m < 2; m++)
#pragma unroll
        for (int kh = 0; kh < 2; kh++) {
            const size_t off = (size_t)(b * TT + qt * 128 + w * 32 + m * 16 + l15) * DM
                             + h * HD + kh * 32 + g * 8;
            qh[m][kh] = *(const bf8_t*)(Qhg + off);
            ql[m][kh] = *(const bf8_t*)(Qlg + off);
        }

    f4_t o[2][4] = {};
    float lrow[2] = {0.f, 0.f};

    bf8_t pk[2], pkl[2], pv[2], pvl[2];
    auto ISSUE = [&](int kt) {
#pragma unroll
        for (int j = 0; j < 2; j++) {
            const int u = tid + j * 256, r = u >> 3, c = u & 7;
            const size_t ko = (size_t)(b * TT + kt * 64 + r) * DM + h * HD + c * 8;
            pk[j]  = *(const bf8_t*)(Khg + ko);
            pkl[j] = *(const bf8_t*)(Klg + ko);
            const size_t vo = (size_t)(h * HD + r) * MROWS + b * TT + kt * 64 + c * 8;
            pv[j]  = *(const bf8_t*)(Vhg + vo);
            pvl[j] = *(const bf8_t*)(Vlg + vo);
        }
    };

    const int nkt = 2 * qt + 2;
    ISSUE(0);
    for (int kt = 0; kt < nkt; kt++) {
        __syncthreads();   // previous tile's LDS readers done
#pragma unroll
        for (int j = 0; j < 2; j++) {
            const int u = tid + j * 256, r = u >> 3, c = u & 7;
            *(bf8_t*)(sm +         swz(r, c * 16)) = pk[j];
            *(bf8_t*)(sm +  8192 + swz(r, c * 16)) = pkl[j];
            *(bf8_t*)(sm + 16384 + swz(r, c * 16)) = pv[j];
            *(bf8_t*)(sm + 24576 + swz(r, c * 16)) = pvl[j];
        }
        __syncthreads();
        if (kt + 1 < nkt) ISSUE(kt + 1);   // in flight under the tile compute

        // ---- S^T = K Q^T (per m-group): row k_local = n*16+g*4+r, col = q ----
        f4_t s[2][4] = {};
        __builtin_amdgcn_s_setprio(1);
#pragma unroll
        for (int kh = 0; kh < 2; kh++) {
#pragma unroll
            for (int n = 0; n < 4; n++) {
                bf8_t kf  = *(const bf8_t*)(sm +        swz(n * 16 + l15, kh * 64 + g * 16));
                bf8_t kl2 = *(const bf8_t*)(sm + 8192 + swz(n * 16 + l15, kh * 64 + g * 16));
#pragma unroll
                for (int m = 0; m < 2; m++) {
                    s[m][n] = __builtin_amdgcn_mfma_f32_16x16x32_bf16(kf,  qh[m][kh], s[m][n], 0, 0, 0);
                    s[m][n] = __builtin_amdgcn_mfma_f32_16x16x32_bf16(kl2, qh[m][kh], s[m][n], 0, 0, 0);
                    s[m][n] = __builtin_amdgcn_mfma_f32_16x16x32_bf16(kf,  ql[m][kh], s[m][n], 0, 0, 0);
                }
            }
        }
        __builtin_amdgcn_s_setprio(0);

        // ---- causal mask (tiles overlapping the diagonal) ----
        if (kt >= 2 * qt) {
            const int koff = (kt - 2 * qt) * 64;
#pragma unroll
            for (int m = 0; m < 2; m++) {
                const int qloc = w * 32 + m * 16 + l15;
#pragma unroll
                for (int n = 0; n < 4; n++)
#pragma unroll
                    for (int r = 0; r < 4; r++)
                        if (koff + n * 16 + g * 4 + r > qloc) s[m][n][r] = -INFINITY;
            }
        }

        // ---- fixed-max softmax: p = exp(s - 8); per-lane partial l ----
#pragma unroll
        for (int m = 0; m < 2; m++)
#pragma unroll
            for (int n = 0; n < 4; n++) {
                bf4_t hv, lv;
#pragma unroll
                for (int r = 0; r < 4; r++) {
                    const float p = __expf(s[m][n][r] - 8.0f);
                    lrow[m] += p;
                    __bf16 hb = (__bf16)p;
                    hv[r] = hb;
                    lv[r] = (__bf16)(p - (float)hb);
                }
                *(bf4_t*)(pb +        swz(m * 16 + l15, n * 32 + g * 8)) = hv;
                *(bf4_t*)(pb + 4096 + swz(m * 16 + l15, n * 32 + g * 8)) = lv;
            }
        asm volatile("s_waitcnt lgkmcnt(0)" ::: "memory");
        __builtin_amdgcn_sched_barrier(0);

        // ---- P A-fragments from LDS ----
        bf8_t pah[2][2], pal2[2][2];
#pragma unroll
        for (int m = 0; m < 2; m++)
#pragma unroll
            for (int kh = 0; kh < 2; kh++) {
                pah[m][kh]  = *(const bf8_t*)(pb +        swz(m * 16 + l15, kh * 64 + g * 16));
                pal2[m][kh] = *(const bf8_t*)(pb + 4096 + swz(m * 16 + l15, kh * 64 + g * 16));
            }

        // ---- O += P V (3-term) ----
        __builtin_amdgcn_s_setprio(1);
#pragma unroll
        for (int kh = 0; kh < 2; kh++)
#pragma unroll
            for (int nf = 0; nf < 4; nf++) {
                bf8_t vf  = *(const bf8_t*)(sm + 16384 + swz(nf * 16 + l15, kh * 64 + g * 16));
                bf8_t vl2 = *(const bf8_t*)(sm + 24576 + swz(nf * 16 + l15, kh * 64 + g * 16));
#pragma unroll
                for (int m = 0; m < 2; m++) {
                    o[m][nf] = __builtin_amdgcn_mfma_f32_16x16x32_bf16(pah[m][kh],  vf,  o[m][nf], 0, 0, 0);
                    o[m][nf] = __builtin_amdgcn_mfma_f32_16x16x32_bf16(pal2[m][kh], vf,  o[m][nf], 0, 0, 0);
                    o[m][nf] = __builtin_amdgcn_mfma_f32_16x16x32_bf16(pah[m][kh],  vl2, o[m][nf], 0, 0, 0);
                }
            }
        __builtin_amdgcn_s_setprio(0);
    }

    // ---- final l reduce + normalize + split + coalesced store ----
    float linv[2][4];
#pragma unroll
    for (int m = 0; m < 2; m++) {
        lrow[m] += __shfl_xor(lrow[m], 16);
        lrow[m] += __shfl_xor(lrow[m], 32);
        const float inv = 1.0f / lrow[m];
#pragma unroll
        for (int r = 0; r < 4; r++)
            linv[m][r] = __shfl(inv, (lane & 48) | (g * 4 + r));
    }

#pragma unroll
    for (int m = 0; m < 2; m++)
#pragma unroll
        for (int nf = 0; nf < 4; nf++)
#pragma unroll
            for (int r = 0; r < 4; r++) {
                const float val = o[m][nf][r] * linv[m][r];
                __bf16 hb = (__bf16)val;
                const int row = m * 16 + g * 4 + r;
                *(__bf16*)(pb + row * 128 + (nf * 16 + l15) * 2) = hb;
                *(__bf16*)(pb + 4096 + row * 128 + (nf * 16 + l15) * 2) =
                    (__bf16)(val - (float)hb);
            }
    asm volatile("s_waitcnt lgkmcnt(0)" ::: "memory");
    __builtin_amdgcn_sched_barrier(0);
#pragma unroll
    for (int j = 0; j < 4; j++) {
        const int u = lane + j * 64, r = u >> 3, c = u & 7;
        const size_t off = (size_t)(b * TT + qt * 128 + w * 32 + r) * DM
                         + h * HD + c * 8;
        *(bf8_t*)(Aoh + off) = *(const bf8_t*)(pb + r * 128 + c * 16);
        *(bf8_t*)(Aol + off) = *(const bf8_t*)(pb + 4096 + r * 128 + c * 16);
    }
}

// ---------------------------------------------------------------------------
extern "C" void kernel_launch(void* const* d_in, const int* in_sizes, int n_in,
                              void* d_out, int out_size, void* d_ws, size_t ws_size,
                              hipStream_t stream) {
    const void* x  = d_in[0];
    const void* wq = d_in[1];
    const void* wk = d_in[2];
    const void* wv = d_in[3];
    const void* wo = d_in[4];

    __bf16* Qh  = (__bf16*)d_ws;
    __bf16* Kh  = Qh + 2 * PL;
    __bf16* Vth = Kh + 2 * PL;
    __bf16* Xh  = Vth + 2 * PL;           // X planes -> reused as Ao planes
    __bf16* Wsp = Xh + 2 * PL;
    char* tail  = (char*)(Wsp + 8 * PLW);
    int* flag   = (int*)tail;
    float2* trig = (float2*)(tail + 512);

    prep<<<8449, 256, 0, stream>>>(x, wq, wk, wv, wo, Xh, Wsp, trig, flag);

    gemm_fused<<<dim3(DM / 64, MROWS / 128, 3), 256, 0, stream>>>(
        Xh, Wsp, Qh, Kh, Vth, nullptr, trig, flag, 0);

    flash_attn_mfma<<<dim3(16, NH, BB), 256, 0, stream>>>(Qh, Kh, Vth, Xh);

    gemm_fused<<<dim3(DM / 64, MROWS / 128, 1), 256, 0, stream>>>(
        Xh, Wsp, nullptr, nullptr, nullptr, d_out, trig, flag, 1);
}

// Round 12
// 277.790 us; speedup vs baseline: 1.1737x; 1.1737x over previous
//
#include <hip/hip_runtime.h>
#include <hip/hip_bf16.h>
#include <math.h>

#define DM 1024
#define NH 16
#define HD 64
#define BB 2
#define TT 2048
#define MROWS (BB*TT)   // 4096
#define PL ((size_t)MROWS * DM)   // elements per activation plane (4 Mi)
#define PLW ((size_t)DM * DM)     // elements per weight plane (1 Mi)

using bf8_t = __attribute__((ext_vector_type(8))) __bf16;   // one MFMA A/B fragment (4 VGPRs)
using bf4_t = __attribute__((ext_vector_type(4))) __bf16;   // 8-byte LDS/global chunk
using f4_t  = __attribute__((ext_vector_type(4))) float;    // MFMA C/D fragment

typedef const __attribute__((address_space(1))) void* gas_t;
typedef __attribute__((address_space(3))) void* las_t;

// ---------------------------------------------------------------------------
// Fused prep (unchanged from round 10).
// ---------------------------------------------------------------------------
__global__ __launch_bounds__(256) void prep(
        const void* __restrict__ X,
        const void* __restrict__ w0, const void* __restrict__ w1,
        const void* __restrict__ w2, const void* __restrict__ w3,
        __bf16* __restrict__ Xh, __bf16* __restrict__ Wsp,
        float2* __restrict__ trig, int* __restrict__ flag)
{
    const int id  = (int)blockIdx.x;
    const int tid = (int)threadIdx.x;

    __shared__ int cnt;
    if (tid == 0) cnt = 0;
    __syncthreads();
    {
        int local = 0;
        const unsigned short* xu = (const unsigned short*)X;
        for (int i = tid; i < 512; i += 256) {
            const int e = (xu[i] >> 7) & 0xFF;
            if (e >= 117 && e <= 130) local++;
        }
        atomicAdd(&cnt, local);
    }
    __syncthreads();
    const int f32 = (cnt >= 384) ? 0 : 1;

    if (id >= 8448) {
        if (tid == 0) *flag = f32;
        return;
    }
    if (id >= 8192) {
        const int idx = (id - 8192) * 256 + tid;
        const int t = idx >> 5, ip = idx & 31;
        const float inv_freq = powf(10000.0f, -2.0f * (float)ip / 64.0f);
        const float ang = (float)t * inv_freq;
        float s, c;
        sincosf(ang, &s, &c);
        trig[idx] = make_float2(c, s);
        return;
    }

    const void* Src;
    __bf16 *Yh, *Yl;
    size_t i;
    if (id < 4096) {
        Src = X;
        Yh = Xh; Yl = Xh + PL;
        i = ((size_t)id * 256 + tid) * 4;
    } else {
        const int wid   = (id - 4096) >> 10;
        const int inner = (id - 4096) & 1023;
        Src = (wid == 0) ? w0 : (wid == 1) ? w1 : (wid == 2) ? w2 : w3;
        Yh = Wsp + (size_t)wid * 2 * PLW;
        Yl = Yh + PLW;
        i = ((size_t)inner * 256 + tid) * 4;
    }
    if (f32) {
        float4 v = *(const float4*)((const float*)Src + i);
        __bf16 h0 = (__bf16)v.x, h1 = (__bf16)v.y, h2 = (__bf16)v.z, h3 = (__bf16)v.w;
        bf4_t hv = {h0, h1, h2, h3};
        bf4_t lv = {(__bf16)(v.x - (float)h0), (__bf16)(v.y - (float)h1),
                    (__bf16)(v.z - (float)h2), (__bf16)(v.w - (float)h3)};
        *(bf4_t*)(Yh + i) = hv;
        *(bf4_t*)(Yl + i) = lv;
    } else {
        bf4_t v = *(const bf4_t*)((const __bf16*)Src + i);
        *(bf4_t*)(Yh + i) = v;
        bf4_t zv = {(__bf16)0.f, (__bf16)0.f, (__bf16)0.f, (__bf16)0.f};
        *(bf4_t*)(Yl + i) = zv;
    }
}

// ---------------------------------------------------------------------------
// XCD-aware bijective block remap (T1, nwg % 8 == 0 for all grids).
// ---------------------------------------------------------------------------
__device__ __forceinline__ int xcd_remap(int flat, int nwg) {
    return (flat & 7) * (nwg >> 3) + (flat >> 3);
}

__device__ __forceinline__ int swz(int r, int b) {
    return r * 128 + (b ^ ((r & 7) << 4));
}
#define VST 264

// ---------------------------------------------------------------------------
// MFMA GEMM v12: global_load_lds width-16 staging with LINEAR LDS dest +
// XOR-permuted per-lane global SOURCE (c_src = c ^ (r&7)) + SWIZZLED reads
// (rule 21 both-sides pattern, m201-verified).  LDS image is byte-identical
// to round-10's reg-staged version, so compute/epilogue are verbatim
// round 10 (98 us, bank-conflict 5e5).  Source permutation keeps full
// coalescing (chunks reordered within each 128B row).
// ---------------------------------------------------------------------------
__global__ __launch_bounds__(256, 3) void gemm_fused(
        const __bf16* __restrict__ Ahg,
        const __bf16* __restrict__ Wsp,
        __bf16* __restrict__ Y0, __bf16* __restrict__ Y1,
        __bf16* __restrict__ Y2,
        void* __restrict__ Yout,
        const float2* __restrict__ trig,
        const int* __restrict__ flag, const int outMode)
{
    const int f32 = *flag;

    const int nx = (int)gridDim.x, ny = (int)gridDim.y, nz = (int)gridDim.z;
    int flat = (int)blockIdx.x + nx * ((int)blockIdx.y + ny * (int)blockIdx.z);
    flat = xcd_remap(flat, nx * ny * nz);
    const int bx = flat % nx;
    const int rem = flat / nx;
    const int by = rem % ny;
    const int z  = rem / ny;

    const int widx = outMode ? 3 : z;
    const __bf16* Whg = Wsp + (size_t)widx * 2 * PLW;
    const __bf16* Wlg = Whg + PLW;
    const __bf16* Alg = Ahg + PL;
    const bool aLo = (outMode != 0) || (f32 != 0);
    const bool wLo = (f32 != 0);

    __shared__ __align__(16) char sm[49152];
    char* const AhL = sm;            // [128][64] bf16 (16 KB), swizzled image
    char* const AlL = sm + 16384;
    char* const WhL = sm + 32768;    // [64][64] bf16 (8 KB)
    char* const WlL = sm + 40960;

    const int tid  = threadIdx.x;
    const int n0   = bx * 64, m0 = by * 128;
    const int lane = tid & 63;
    const int w    = tid >> 6;
    const int wr   = (w >> 1) * 64;
    const int wcn  = (w & 1) * 32;
    const int l15  = lane & 15;
    const int g    = lane >> 4;

    f4_t acc[4][2] = {};

    for (int k0 = 0; k0 < DM; k0 += 64) {
        if (k0) __syncthreads();     // previous compute done before overwrite

        // ---- stage: linear LDS dest, XOR-permuted global source ----
#pragma unroll
        for (int j = 0; j < 4; j++) {
            const int u = tid + j * 256, r = u >> 3, c = u & 7;
            const int cs = c ^ (r & 7);            // source-chunk permutation
            __builtin_amdgcn_global_load_lds(
                (gas_t)(Ahg + (size_t)(m0 + r) * DM + k0 + cs * 8),
                (las_t)(AhL + (size_t)(j * 256 + w * 64) * 16), 16, 0, 0);
            if (aLo)
                __builtin_amdgcn_global_load_lds(
                    (gas_t)(Alg + (size_t)(m0 + r) * DM + k0 + cs * 8),
                    (las_t)(AlL + (size_t)(j * 256 + w * 64) * 16), 16, 0, 0);
        }
#pragma unroll
        for (int j = 0; j < 2; j++) {
            const int u = tid + j * 256, r = u >> 3, c = u & 7;
            const int cs = c ^ (r & 7);
            __builtin_amdgcn_global_load_lds(
                (gas_t)(Whg + (size_t)(n0 + r) * DM + k0 + cs * 8),
                (las_t)(WhL + (size_t)(j * 256 + w * 64) * 16), 16, 0, 0);
            if (wLo)
                __builtin_amdgcn_global_load_lds(
                    (gas_t)(Wlg + (size_t)(n0 + r) * DM + k0 + cs * 8),
                    (las_t)(WlL + (size_t)(j * 256 + w * 64) * 16), 16, 0, 0);
        }
        __syncthreads();             // vmcnt drain -> data ready

        // ---- compute (swizzled reads, verbatim round 10) ----
#pragma unroll
        for (int kh = 0; kh < 2; kh++) {
            const int bc = kh * 64 + g * 16;
            bf8_t ah[4], al[4], wh[2], wl[2];
#pragma unroll
            for (int m = 0; m < 4; m++) {
                ah[m] = *(const bf8_t*)(AhL + swz(wr + m * 16 + l15, bc));
                if (aLo) al[m] = *(const bf8_t*)(AlL + swz(wr + m * 16 + l15, bc));
            }
#pragma unroll
            for (int n = 0; n < 2; n++) {
                wh[n] = *(const bf8_t*)(WhL + swz(wcn + n * 16 + l15, bc));
                if (wLo) wl[n] = *(const bf8_t*)(WlL + swz(wcn + n * 16 + l15, bc));
            }
#pragma unroll
            for (int m = 0; m < 4; m++)
#pragma unroll
                for (int n = 0; n < 2; n++) {
                    acc[m][n] = __builtin_amdgcn_mfma_f32_16x16x32_bf16(
                                    ah[m], wh[n], acc[m][n], 0, 0, 0);
                    if (aLo)
                        acc[m][n] = __builtin_amdgcn_mfma_f32_16x16x32_bf16(
                                        al[m], wh[n], acc[m][n], 0, 0, 0);
                    if (wLo)
                        acc[m][n] = __builtin_amdgcn_mfma_f32_16x16x32_bf16(
                                        ah[m], wl[n], acc[m][n], 0, 0, 0);
                }
        }
    }

    const int orow = g * 4;
    const int ocol = l15;
    __syncthreads();

    if (outMode) {
        if (f32) {
#pragma unroll
            for (int m = 0; m < 4; m++)
#pragma unroll
                for (int n = 0; n < 2; n++) {
                    const int gr = m0 + wr + m * 16 + orow;
                    const int gc = n0 + wcn + n * 16 + ocol;
#pragma unroll
                    for (int r = 0; r < 4; r++)
                        ((float*)Yout)[(size_t)(gr + r) * DM + gc] = acc[m][n][r];
                }
        } else {
            char* const EhL = sm;
#pragma unroll
            for (int m = 0; m < 4; m++)
#pragma unroll
                for (int n = 0; n < 2; n++) {
                    const int ctile = wcn + n * 16 + ocol;
#pragma unroll
                    for (int r = 0; r < 4; r++) {
                        const int rtile = wr + m * 16 + orow + r;
                        *(__bf16*)(EhL + rtile * 128 + ctile * 2) = (__bf16)acc[m][n][r];
                    }
                }
            __syncthreads();
#pragma unroll
            for (int j = 0; j < 4; j++) {
                const int u = tid + j * 256, r = u >> 3, c = u & 7;
                *(bf8_t*)((__bf16*)Yout + (size_t)(m0 + r) * DM + n0 + c * 8) =
                    *(const bf8_t*)(EhL + r * 128 + c * 16);
            }
        }
    } else if (z == 2) {
        char* const EhL = sm;
        char* const ElL = sm + 20480;
#pragma unroll
        for (int m = 0; m < 4; m++)
#pragma unroll
            for (int n = 0; n < 2; n++) {
                const int ctile = wcn + n * 16 + ocol;
#pragma unroll
                for (int r = 0; r < 4; r++) {
                    const int rtile = wr + m * 16 + orow + r;
                    const float val = acc[m][n][r];
                    __bf16 hb = (__bf16)val;
                    *(__bf16*)(EhL + ctile * VST + rtile * 2) = hb;
                    *(__bf16*)(ElL + ctile * VST + rtile * 2) = (__bf16)(val - (float)hb);
                }
            }
        __syncthreads();
        __bf16* Vh = Y2;
        __bf16* Vl = Y2 + PL;
#pragma unroll
        for (int j = 0; j < 4; j++) {
            const int u = tid + j * 256, cc = u >> 4, k = u & 15;
            *(bf8_t*)(Vh + (size_t)(n0 + cc) * MROWS + m0 + k * 8) =
                *(const bf8_t*)(EhL + cc * VST + k * 16);
            *(bf8_t*)(Vl + (size_t)(n0 + cc) * MROWS + m0 + k * 8) =
                *(const bf8_t*)(ElL + cc * VST + k * 16);
        }
    } else {
        char* const EhL = sm;
        char* const ElL = sm + 20480;
#pragma unroll
        for (int m = 0; m < 4; m++)
#pragma unroll
            for (int n = 0; n < 2; n++) {
                const int ctile = wcn + n * 16 + ocol;
                const int gc = n0 + ctile;
                const int ip = (gc & 63) >> 1;
                const bool oddc = (gc & 1) != 0;
#pragma unroll
                for (int r = 0; r < 4; r++) {
                    const int rtile = wr + m * 16 + orow + r;
                    const int t = (m0 + rtile) & (TT - 1);
                    const float2 cs = trig[t * 32 + ip];
                    const float v = acc[m][n][r];
                    const float ov = __shfl_xor(v, 1);
                    float res = oddc ? (ov * cs.y + v * cs.x) : (v * cs.x - ov * cs.y);
                    if (z == 0) res *= 0.125f;
                    __bf16 hb = (__bf16)res;
                    *(__bf16*)(EhL + rtile * 128 + ctile * 2) = hb;
                    *(__bf16*)(ElL + rtile * 128 + ctile * 2) = (__bf16)(res - (float)hb);
                }
            }
        __syncthreads();
        __bf16* Yh = z ? Y1 : Y0;
        __bf16* Yl = Yh + PL;
#pragma unroll
        for (int j = 0; j < 4; j++) {
            const int u = tid + j * 256, r = u >> 3, c = u & 7;
            *(bf8_t*)(Yh + (size_t)(m0 + r) * DM + n0 + c * 8) =
                *(const bf8_t*)(EhL + r * 128 + c * 16);
            *(bf8_t*)(Yl + (size_t)(m0 + r) * DM + n0 + c * 8) =
                *(const bf8_t*)(ElL + r * 128 + c * 16);
        }
    }
}

// ---------------------------------------------------------------------------
// MFMA flash attention: round-10 version verbatim (best measured ~89 us).
// Fixed-max softmax, P via wave-private LDS, write-late KV double-buffer,
// paired-qt equal-length blocks, XCD remap, setprio around MFMA clusters.
// ---------------------------------------------------------------------------
__global__ void __launch_bounds__(256, 2) flash_attn_mfma(
        const __bf16* __restrict__ Qhg, const __bf16* __restrict__ Khg,
        const __bf16* __restrict__ Vhg, __bf16* __restrict__ Aoh)
{
    __shared__ __align__(16) char sm[81920];
    // KV buffer p at sm + p*32768: Kh +0, Kl +8192, Vh +16384, Vl +24576
    // P/epilogue region: sm + 65536 + w*4096 (hi @0, lo @2048)

    const __bf16* Qlg = Qhg + PL;
    const __bf16* Klg = Khg + PL;
    const __bf16* Vlg = Vhg + PL;
    __bf16* Aol = Aoh + PL;

    int flat = (int)blockIdx.x + 16 * ((int)blockIdx.y + 16 * (int)blockIdx.z);
    flat = xcd_remap(flat, 512);
    const int pi = flat % 16;
    const int h  = (flat / 16) % 16;
    const int b  = flat / 256;

    const int tid = threadIdx.x;
    const int lane = tid & 63;
    const int w    = tid >> 6;
    const int l15  = lane & 15;
    const int g    = lane >> 4;

    char* const pb = sm + 65536 + w * 4096;   // wave-private P buffer

    bf8_t pk[2], pkl[2], pv[2], pvl[2];
    auto ISSUE = [&](int kt) {
#pragma unroll
        for (int j = 0; j < 2; j++) {
            const int u = tid + j * 256, r = u >> 3, c = u & 7;
            const size_t ko = (size_t)(b * TT + kt * 64 + r) * DM + h * HD + c * 8;
            pk[j]  = *(const bf8_t*)(Khg + ko);
            pkl[j] = *(const bf8_t*)(Klg + ko);
            const size_t vo = (size_t)(h * HD + r) * MROWS + b * TT + kt * 64 + c * 8;
            pv[j]  = *(const bf8_t*)(Vhg + vo);
            pvl[j] = *(const bf8_t*)(Vlg + vo);
        }
    };
    auto WRITE = [&](char* base) {
#pragma unroll
        for (int j = 0; j < 2; j++) {
            const int u = tid + j * 256, r = u >> 3, c = u & 7;
            *(bf8_t*)(base +         swz(r, c * 16)) = pk[j];
            *(bf8_t*)(base +  8192 + swz(r, c * 16)) = pkl[j];
            *(bf8_t*)(base + 16384 + swz(r, c * 16)) = pv[j];
            *(bf8_t*)(base + 24576 + swz(r, c * 16)) = pvl[j];
        }
    };

#pragma unroll 1
    for (int ph = 0; ph < 2; ph++) {
        const int qt = ph ? pi : (31 - pi);

        bf8_t qh[2], ql[2];
#pragma unroll
        for (int kh = 0; kh < 2; kh++) {
            const size_t off = (size_t)(b * TT + qt * 64 + w * 16 + l15) * DM
                             + h * HD + kh * 32 + g * 8;
            qh[kh] = *(const bf8_t*)(Qhg + off);
            ql[kh] = *(const bf8_t*)(Qlg + off);
        }

        f4_t o[4] = {};
        float lrow = 0.f;

        ISSUE(0);
        WRITE(sm);
        __syncthreads();

        for (int kt = 0; kt <= qt; kt++) {
            char* const cb = sm + (kt & 1) * 32768;
            if (kt < qt) ISSUE(kt + 1);

            f4_t s[4] = {};
            __builtin_amdgcn_s_setprio(1);
#pragma unroll
            for (int kh = 0; kh < 2; kh++) {
#pragma unroll
                for (int n = 0; n < 4; n++) {
                    bf8_t kf  = *(const bf8_t*)(cb +        swz(n * 16 + l15, kh * 64 + g * 16));
                    bf8_t kl2 = *(const bf8_t*)(cb + 8192 + swz(n * 16 + l15, kh * 64 + g * 16));
                    s[n] = __builtin_amdgcn_mfma_f32_16x16x32_bf16(kf,  qh[kh], s[n], 0, 0, 0);
                    s[n] = __builtin_amdgcn_mfma_f32_16x16x32_bf16(kl2, qh[kh], s[n], 0, 0, 0);
                    s[n] = __builtin_amdgcn_mfma_f32_16x16x32_bf16(kf,  ql[kh], s[n], 0, 0, 0);
                }
            }
            __builtin_amdgcn_s_setprio(0);

            if (kt == qt) {
                const int qoff = w * 16 + l15;
#pragma unroll
                for (int n = 0; n < 4; n++)
#pragma unroll
                    for (int r = 0; r < 4; r++)
                        if (n * 16 + g * 4 + r > qoff) s[n][r] = -INFINITY;
            }

#pragma unroll
            for (int n = 0; n < 4; n++) {
                bf4_t hv, lv;
#pragma unroll
                for (int r = 0; r < 4; r++) {
                    const float p = __expf(s[n][r] - 8.0f);
                    lrow += p;
                    __bf16 hb = (__bf16)p;
                    hv[r] = hb;
                    lv[r] = (__bf16)(p - (float)hb);
                }
                *(bf4_t*)(pb +        swz(l15, n * 32 + g * 8)) = hv;
                *(bf4_t*)(pb + 2048 + swz(l15, n * 32 + g * 8)) = lv;
            }
            asm volatile("s_waitcnt lgkmcnt(0)" ::: "memory");
            __builtin_amdgcn_sched_barrier(0);

            bf8_t pah[2], pal2[2];
#pragma unroll
            for (int kh = 0; kh < 2; kh++) {
                pah[kh]  = *(const bf8_t*)(pb +        swz(l15, kh * 64 + g * 16));
                pal2[kh] = *(const bf8_t*)(pb + 2048 + swz(l15, kh * 64 + g * 16));
            }

            __builtin_amdgcn_s_setprio(1);
#pragma unroll
            for (int kh = 0; kh < 2; kh++)
#pragma unroll
                for (int nf = 0; nf < 4; nf++) {
                    bf8_t vf  = *(const bf8_t*)(cb + 16384 + swz(nf * 16 + l15, kh * 64 + g * 16));
                    bf8_t vl2 = *(const bf8_t*)(cb + 24576 + swz(nf * 16 + l15, kh * 64 + g * 16));
                    o[nf] = __builtin_amdgcn_mfma_f32_16x16x32_bf16(pah[kh],  vf,  o[nf], 0, 0, 0);
                    o[nf] = __builtin_amdgcn_mfma_f32_16x16x32_bf16(pal2[kh], vf,  o[nf], 0, 0, 0);
                    o[nf] = __builtin_amdgcn_mfma_f32_16x16x32_bf16(pah[kh],  vl2, o[nf], 0, 0, 0);
                }
            __builtin_amdgcn_s_setprio(0);

            if (kt < qt) WRITE(sm + ((kt + 1) & 1) * 32768);
            __syncthreads();
        }

        lrow += __shfl_xor(lrow, 16);
        lrow += __shfl_xor(lrow, 32);
        const float inv = 1.0f / lrow;
        float linv[4];
#pragma unroll
        for (int r = 0; r < 4; r++)
            linv[r] = __shfl(inv, (lane & 48) | (g * 4 + r));

#pragma unroll
        for (int nf = 0; nf < 4; nf++)
#pragma unroll
            for (int r = 0; r < 4; r++) {
                const float val = o[nf][r] * linv[r];
                __bf16 hb = (__bf16)val;
                *(__bf16*)(pb + (g * 4 + r) * 128 + (nf * 16 + l15) * 2) = hb;
                *(__bf16*)(pb + 2048 + (g * 4 + r) * 128 + (nf * 16 + l15) * 2) =
                    (__bf16)(val - (float)hb);
            }
        asm volatile("s_waitcnt lgkmcnt(0)" ::: "memory");
        __builtin_amdgcn_sched_barrier(0);
#pragma unroll
        for (int j = 0; j < 2; j++) {
            const int u = lane + j * 64, r = u >> 3, c = u & 7;
            const size_t off = (size_t)(b * TT + qt * 64 + w * 16 + r) * DM
                             + h * HD + c * 8;
            *(bf8_t*)(Aoh + off) = *(const bf8_t*)(pb + r * 128 + c * 16);
            *(bf8_t*)(Aol + off) = *(const bf8_t*)(pb + 2048 + r * 128 + c * 16);
        }
    }
}

// ---------------------------------------------------------------------------
extern "C" void kernel_launch(void* const* d_in, const int* in_sizes, int n_in,
                              void* d_out, int out_size, void* d_ws, size_t ws_size,
                              hipStream_t stream) {
    const void* x  = d_in[0];
    const void* wq = d_in[1];
    const void* wk = d_in[2];
    const void* wv = d_in[3];
    const void* wo = d_in[4];

    __bf16* Qh  = (__bf16*)d_ws;
    __bf16* Kh  = Qh + 2 * PL;
    __bf16* Vth = Kh + 2 * PL;
    __bf16* Xh  = Vth + 2 * PL;           // X planes -> reused as Ao planes
    __bf16* Wsp = Xh + 2 * PL;
    char* tail  = (char*)(Wsp + 8 * PLW);
    int* flag   = (int*)tail;
    float2* trig = (float2*)(tail + 512);

    prep<<<8449, 256, 0, stream>>>(x, wq, wk, wv, wo, Xh, Wsp, trig, flag);

    gemm_fused<<<dim3(DM / 64, MROWS / 128, 3), 256, 0, stream>>>(
        Xh, Wsp, Qh, Kh, Vth, nullptr, trig, flag, 0);

    flash_attn_mfma<<<dim3(16, NH, BB), 256, 0, stream>>>(Qh, Kh, Vth, Xh);

    gemm_fused<<<dim3(DM / 64, MROWS / 128, 1), 256, 0, stream>>>(
        Xh, Wsp, nullptr, nullptr, nullptr, d_out, trig, flag, 1);
}